// Round 6
// baseline (385.946 us; speedup 1.0000x reference)
//
#include <hip/hip_runtime.h>
#include <hip/hip_bf16.h>

typedef __bf16 bf16_t;
typedef __bf16 bf16x8_t __attribute__((ext_vector_type(8)));
typedef float f32x4_t __attribute__((ext_vector_type(4)));

static constexpr int B_ = 2, S_ = 2048, D_ = 512, H_ = 8, DK_ = 64, DFF_ = 2048;
static constexpr int M_ = B_ * S_;  // 4096 tokens
static constexpr float QSCALE = 0.125f * 1.44269504f;  // 1/sqrt(dk) * log2(e)

// partial-drain barrier: waits until <=N of this wave's global_load_lds remain
// in flight, then block-barrier. Loads beyond N stay in flight ACROSS the
// barrier (the hipBLASLt-style pipeline __syncthreads() cannot express).
#define VMCNT_BARRIER(N) asm volatile("s_waitcnt vmcnt(" #N ")\n\ts_barrier" ::: "memory")

__device__ __forceinline__ unsigned pkbf(float a, float b) {
  union { bf16_t h; unsigned short u; } x, y;
  x.h = (bf16_t)a; y.h = (bf16_t)b;
  return (unsigned)x.u | ((unsigned)y.u << 16);
}

// async global->LDS, 16B per lane. LDS dest = wave-uniform base + lane*16.
__device__ __forceinline__ void async16(bf16_t* lds, const bf16_t* g) {
  __builtin_amdgcn_global_load_lds((__attribute__((address_space(1))) void*)g,
                                   (__attribute__((address_space(3))) void*)lds,
                                   16, 0, 0);
}

// ---------------------------------------------------------------------------
// LayerNorm (torch style, ddof=1). fp32 in -> bf16 out. 1 wave/row.
// ---------------------------------------------------------------------------
__global__ __launch_bounds__(256) void ln_kernel(const float* __restrict__ x,
                                                 const float* __restrict__ ga,
                                                 const float* __restrict__ gb,
                                                 bf16_t* __restrict__ out) {
  const int row = blockIdx.x * 4 + (threadIdx.x >> 6);
  const int lane = threadIdx.x & 63;
  const float4* xr = (const float4*)(x + (long)row * D_);
  float4 v0 = xr[lane * 2];
  float4 v1 = xr[lane * 2 + 1];
  float s = v0.x + v0.y + v0.z + v0.w + v1.x + v1.y + v1.z + v1.w;
  float ss = v0.x * v0.x + v0.y * v0.y + v0.z * v0.z + v0.w * v0.w +
             v1.x * v1.x + v1.y * v1.y + v1.z * v1.z + v1.w * v1.w;
#pragma unroll
  for (int m = 1; m < 64; m <<= 1) {
    s += __shfl_xor(s, m);
    ss += __shfl_xor(ss, m);
  }
  const float mean = s * (1.0f / 512.0f);
  float var = (ss - 512.0f * mean * mean) * (1.0f / 511.0f);
  var = fmaxf(var, 0.0f);
  const float sc = ga[0] / (sqrtf(var) + 1e-6f);
  const float sh = gb[0] - mean * sc;
  alignas(16) bf16_t y[8];
  y[0] = (bf16_t)(v0.x * sc + sh);
  y[1] = (bf16_t)(v0.y * sc + sh);
  y[2] = (bf16_t)(v0.z * sc + sh);
  y[3] = (bf16_t)(v0.w * sc + sh);
  y[4] = (bf16_t)(v1.x * sc + sh);
  y[5] = (bf16_t)(v1.y * sc + sh);
  y[6] = (bf16_t)(v1.z * sc + sh);
  y[7] = (bf16_t)(v1.w * sc + sh);
  ((uint4*)(out + (long)row * D_))[lane] = *(uint4*)y;
}

// ---------------------------------------------------------------------------
__global__ __launch_bounds__(256) void cvt_bf16(const float* __restrict__ x,
                                                bf16_t* __restrict__ y) {
  const long i = ((long)blockIdx.x * 256 + threadIdx.x) * 8;
  float4 a = *(const float4*)(x + i);
  float4 b = *(const float4*)(x + i + 4);
  alignas(16) bf16_t t[8];
  t[0] = (bf16_t)a.x; t[1] = (bf16_t)a.y; t[2] = (bf16_t)a.z; t[3] = (bf16_t)a.w;
  t[4] = (bf16_t)b.x; t[5] = (bf16_t)b.y; t[6] = (bf16_t)b.z; t[7] = (bf16_t)b.w;
  *(uint4*)(y + i) = *(uint4*)t;
}

// ---------------------------------------------------------------------------
// Weight convert+transpose: W[K][N] fp32 -> Wt[N][K] bf16, 64x64 tiles.
// ---------------------------------------------------------------------------
__device__ __forceinline__ void wtrans_body(const float* __restrict__ W,
                                            bf16_t* __restrict__ Wt, int K, int N,
                                            int k0, int n0) {
  constexpr int LDT = 65;
  __shared__ float T[64 * LDT];
  const int tid = threadIdx.x;
#pragma unroll
  for (int p = 0; p < 4; ++p) {
    int e = p * 1024 + tid * 4;
    int kr = e >> 6, nc = e & 63;
    float4 f = *(const float4*)(W + (long)(k0 + kr) * N + n0 + nc);
    T[kr * LDT + nc + 0] = f.x;
    T[kr * LDT + nc + 1] = f.y;
    T[kr * LDT + nc + 2] = f.z;
    T[kr * LDT + nc + 3] = f.w;
  }
  __syncthreads();
#pragma unroll
  for (int p = 0; p < 4; ++p) {
    int e = p * 1024 + tid * 4;
    int nr = e >> 6, kc = e & 63;
    alignas(8) bf16_t t[4];
#pragma unroll
    for (int j = 0; j < 4; ++j) t[j] = (bf16_t)T[(kc + j) * LDT + nr];
    *(uint2*)(Wt + (long)(n0 + nr) * K + k0 + kc) = *(uint2*)t;
  }
}

struct WPA { const float* W[10]; bf16_t* T[10]; };
__global__ __launch_bounds__(256) void wprep(WPA a) {
  const int x = blockIdx.x;
  if (x < 512) {        // 8 square 512x512 weights
    const int wi = x >> 6, t = x & 63;
    wtrans_body(a.W[wi], a.T[wi], 512, 512, (t >> 3) * 64, (t & 7) * 64);
  } else if (x < 768) { // ff_W1 512x2048
    const int t = x - 512;
    wtrans_body(a.W[8], a.T[8], 512, 2048, (t & 7) * 64, (t >> 3) * 64);
  } else {              // ff_W2 2048x512
    const int t = x - 768;
    wtrans_body(a.W[9], a.T[9], 2048, 512, (t & 31) * 64, (t >> 5) * 64);
  }
}

// ---------------------------------------------------------------------------
// V transpose for attention: v[token][512] -> vt[bh][64 d][2048 s] (bf16)
// ---------------------------------------------------------------------------
__global__ __launch_bounds__(256) void vtrans(const bf16_t* __restrict__ v,
                                              bf16_t* __restrict__ vt) {
  constexpr int LDT = 66;
  __shared__ bf16_t T[64 * LDT];  // [d][s_local]
  const int tid = threadIdx.x;
  const int bh = blockIdx.y, b = bh >> 3, h = bh & 7;
  const int s0 = blockIdx.x * 64;
#pragma unroll
  for (int p = 0; p < 2; ++p) {
    int e = p * 2048 + tid * 8;
    int sr = e >> 6, c = e & 63;
    uint4 u = *(const uint4*)(v + (long)(b * S_ + s0 + sr) * D_ + h * DK_ + c);
    bf16_t* pv = (bf16_t*)&u;
#pragma unroll
    for (int j = 0; j < 8; ++j) T[(c + j) * LDT + sr] = pv[j];
  }
  __syncthreads();
#pragma unroll
  for (int p = 0; p < 2; ++p) {
    int e = p * 2048 + tid * 8;
    int d = e >> 6, sc = e & 63;
    alignas(16) bf16_t t[8];
#pragma unroll
    for (int j = 0; j < 8; ++j) t[j] = T[d * LDT + sc + j];
    *(uint4*)(vt + ((long)bh * DK_ + d) * S_ + s0 + sc) = *(uint4*)t;
  }
}

// ---------------------------------------------------------------------------
// GEMM: out = act((A @ Wt^T + bias) * oscale) (+res). 64x128 tile, BK=64,
// triple-buffered async LDS staging with prefetch distance 2 and partial
// vmcnt barriers (loads stay in flight across s_barrier). Wave tile 32x64.
// 16B-chunk XOR swizzle (stored chunk c of row r = global chunk c^(r&7)).
// Each wave issues exactly 6 global_load_lds per stage -> vmcnt(6) barrier.
// ---------------------------------------------------------------------------
struct GArg {
  const bf16_t* A;
  const bf16_t* Wt;
  const float* bias;
  const float* res;
  void* out;
  float oscale;
};

template <int MODE>
__global__ __launch_bounds__(256, 2) void gemm_bt(GArg g0, GArg g1, GArg g2,
                                                  int M, int N, int K) {
  __shared__ bf16_t As[3][64 * 64];
  __shared__ bf16_t Bs[3][128 * 64];
  GArg g = (blockIdx.z == 0) ? g0 : (blockIdx.z == 1) ? g1 : g2;
  const int tid = threadIdx.x;
  const int wave = tid >> 6, lane = tid & 63, quad = lane >> 4, l15 = lane & 15;
  const long m0 = (long)blockIdx.x * 64;
  const long n0 = (long)blockIdx.y * 128;
  const int wm = (wave >> 1) * 32;
  const int wn = (wave & 1) * 64;

  // staging: 8 rows x 128B per async16; lane -> row r8=lane>>3,
  // stored chunk lane&7 holds global chunk cg = (lane&7)^r8.
  const int r8 = lane >> 3;
  const int cg = (lane & 7) ^ r8;
  const bf16_t* Ab = g.A + m0 * (long)K + cg * 8;
  const bf16_t* Bb = g.Wt + n0 * (long)K + cg * 8;

  auto stage = [&](int buf, int k0) {
#pragma unroll
    for (int c = 0; c < 2; ++c) {  // A: 16 rows per wave
      const int row = wave * 16 + c * 8;
      async16(&As[buf][row * 64], Ab + (long)(row + r8) * K + k0);
    }
#pragma unroll
    for (int c = 0; c < 4; ++c) {  // B: 32 rows per wave
      const int row = wave * 32 + c * 8;
      async16(&Bs[buf][row * 64], Bb + (long)(row + r8) * K + k0);
    }
  };

  f32x4_t acc[2][4];
#pragma unroll
  for (int i = 0; i < 2; ++i)
#pragma unroll
    for (int j = 0; j < 4; ++j) acc[i][j] = (f32x4_t){0.f, 0.f, 0.f, 0.f};

  const int KT = K >> 6;
  stage(0, 0);
  stage(1, 64);
  int bc = 0;
  for (int kt = 0; kt < KT; ++kt) {
    if (kt + 1 < KT) { VMCNT_BARRIER(6); } else { VMCNT_BARRIER(0); }
    int bs = bc + 2; if (bs >= 3) bs -= 3;
    if (kt + 2 < KT) stage(bs, (kt + 2) * 64);
    const bf16_t* Al = &As[bc][0];
    const bf16_t* Bl = &Bs[bc][0];
    bf16x8_t af[2][2], bfr[2][4];
#pragma unroll
    for (int ks = 0; ks < 2; ++ks) {
      const int sc = ((ks * 4 + quad) ^ (l15 & 7)) * 8;
#pragma unroll
      for (int i = 0; i < 2; ++i)
        af[ks][i] = *(const bf16x8_t*)&Al[(wm + i * 16 + l15) * 64 + sc];
#pragma unroll
      for (int j = 0; j < 4; ++j)
        bfr[ks][j] = *(const bf16x8_t*)&Bl[(wn + j * 16 + l15) * 64 + sc];
    }
#pragma unroll
    for (int ks = 0; ks < 2; ++ks)
#pragma unroll
      for (int i = 0; i < 2; ++i)
#pragma unroll
        for (int j = 0; j < 4; ++j)
          acc[i][j] = __builtin_amdgcn_mfma_f32_16x16x32_bf16(af[ks][i], bfr[ks][j], acc[i][j], 0, 0, 0);
    bc = (bc + 1 == 3) ? 0 : bc + 1;
  }

#pragma unroll
  for (int i = 0; i < 2; ++i) {
#pragma unroll
    for (int j = 0; j < 4; ++j) {
      const long col = n0 + wn + j * 16 + l15;
      const float bv = g.bias[col];
#pragma unroll
      for (int r = 0; r < 4; ++r) {
        const long row = m0 + wm + i * 16 + quad * 4 + r;
        float v = acc[i][j][r] + bv;
        if constexpr (MODE == 1) v = fmaxf(v, 0.f);
        if constexpr (MODE == 2) {
          ((float*)g.out)[row * N + col] = v + g.res[row * N + col];
        } else {
          ((bf16_t*)g.out)[row * N + col] = (bf16_t)(v * g.oscale);
        }
      }
    }
  }
}

// ---------------------------------------------------------------------------
// Flash attention v6: transposed-S, no-max softmax (exp2 domain, Q
// pre-scaled), split-K(2), 128 q-rows per block (wave owns 32 q), k-tile 64.
// Triple-buffered K/V staging, prefetch distance 2, partial vmcnt barriers
// (each wave issues exactly 4 global_load_lds per stage -> vmcnt(4)).
// ---------------------------------------------------------------------------
template <bool CAUSAL>
__global__ __launch_bounds__(256, 2) void flash_attn(const bf16_t* __restrict__ Q,
                                                     const bf16_t* __restrict__ Kg,
                                                     const bf16_t* __restrict__ Vt,
                                                     float* __restrict__ po,
                                                     float* __restrict__ pl) {
  __shared__ bf16_t Ks[3][64 * 64];   // [k][d] swizzled (16B-chunk XOR)
  __shared__ bf16_t Vs[3][64 * 64];   // [d][k] swizzled
  __shared__ bf16_t Ps[4][32 * 64];   // per-wave P[q][k], 16B-chunk XOR
  const int tid = threadIdx.x, wave = tid >> 6, lane = tid & 63;
  const int quad = lane >> 4, l15 = lane & 15;
  const int bh = blockIdx.y, b = bh >> 3, h = bh & 7;
  const int qt = CAUSAL ? (15 - (int)blockIdx.x) : (int)blockIdx.x;
  const int chunk = blockIdx.z;
  const int ntt = CAUSAL ? (2 * qt + 2) : 32;
  const int n0t = ntt >> 1;  // even split, both chunks nonempty
  const int tstart = chunk ? n0t : 0;
  const int tend = chunk ? ntt : n0t;

  const int q0 = qt * 128;
  const int qw = q0 + wave * 32;
  const long base = (long)b * S_ * D_ + (long)h * DK_;
  const long vtbase = (long)bh * DK_ * S_;
  const long prow0 = ((long)(chunk * 16 + bh)) * 2048;

  // Q fragments (B operand): q = qw + qh*16 + l15, k = ks*32 + quad*8
  bf16x8_t qf[2][2];
#pragma unroll
  for (int qh = 0; qh < 2; ++qh)
#pragma unroll
    for (int ks = 0; ks < 2; ++ks)
      qf[qh][ks] = *(const bf16x8_t*)(Q + base + (long)(qw + qh * 16 + l15) * D_ + ks * 32 + quad * 8);

  const int r8 = lane >> 3;
  const int cg8 = (lane & 7) ^ r8;
  const bf16_t* Kb = Kg + base + cg8 * 8;
  const bf16_t* Vb = Vt + vtbase + cg8 * 8;

  auto stage = [&](int buf, int t) {
    const int kk0 = t * 64;
#pragma unroll
    for (int c = 0; c < 2; ++c) {
      const int row = wave * 16 + c * 8;
      async16(&Ks[buf][row * 64], Kb + (long)(kk0 + row + r8) * D_);
      async16(&Vs[buf][row * 64], Vb + (long)(row + r8) * S_ + kk0);
    }
  };

  float li[2] = {0.f, 0.f};
  f32x4_t o[2][4];
#pragma unroll
  for (int qh = 0; qh < 2; ++qh)
#pragma unroll
    for (int db = 0; db < 4; ++db) o[qh][db] = (f32x4_t){0.f, 0.f, 0.f, 0.f};

  bf16_t* Pw = &Ps[wave][0];
  const int pq7 = l15 & 7;

  stage(0, tstart);
  if (tstart + 1 < tend) stage(1, tstart + 1);
  int bc = 0;
  for (int t = tstart; t < tend; ++t) {
    if (t + 1 < tend) { VMCNT_BARRIER(4); } else { VMCNT_BARRIER(0); }
    int bs = bc + 2; if (bs >= 3) bs -= 3;
    if (t + 2 < tend) stage(bs, t + 2);
    const bf16_t* Kt = &Ks[bc][0];
    const bf16_t* Vl = &Vs[bc][0];
    const int kk0 = t * 64;

#pragma unroll
    for (int qh = 0; qh < 2; ++qh) {
      f32x4_t st[4];
#pragma unroll
      for (int nb = 0; nb < 4; ++nb) {
        f32x4_t a = (f32x4_t){0.f, 0.f, 0.f, 0.f};
#pragma unroll
        for (int ks = 0; ks < 2; ++ks) {
          const int scf = ((ks * 4 + quad) ^ (l15 & 7)) * 8;
          const bf16x8_t kf = *(const bf16x8_t*)&Kt[(nb * 16 + l15) * 64 + scf];
          a = __builtin_amdgcn_mfma_f32_16x16x32_bf16(kf, qf[qh][ks], a, 0, 0, 0);
        }
        st[nb] = a;
      }
      const bool domask = CAUSAL && (kk0 + 63 > qw + qh * 16);
#pragma unroll
      for (int nb = 0; nb < 4; ++nb)
#pragma unroll
        for (int r = 0; r < 4; ++r) {
          float v = st[nb][r];  // log2-domain (Q pre-scaled)
          if (domask && (kk0 + nb * 16 + quad * 4 + r > qw + qh * 16 + l15)) v = -1e30f;
          const float p = exp2f(v);
          st[nb][r] = p;
          li[qh] += p;
        }
      // P^T (C layout: k=quad*4+r, q=l15) -> Ps[qh*16+q][k] swizzled
      const int prow = (qh * 16 + l15) * 64;
#pragma unroll
      for (int nb = 0; nb < 4; ++nb) {
        uint2 w;
        w.x = pkbf(st[nb][0], st[nb][1]);
        w.y = pkbf(st[nb][2], st[nb][3]);
        const int ck = nb * 2 + (quad >> 1);
        *(uint2*)&Pw[prow + (ck ^ pq7) * 8 + (quad & 1) * 4] = w;
      }
    }

    bf16x8_t pf[2][2];
#pragma unroll
    for (int qh = 0; qh < 2; ++qh)
#pragma unroll
      for (int ks = 0; ks < 2; ++ks)
        pf[qh][ks] = *(const bf16x8_t*)&Pw[(qh * 16 + l15) * 64 + (((ks * 4 + quad) ^ pq7)) * 8];
#pragma unroll
    for (int ks = 0; ks < 2; ++ks) {
#pragma unroll
      for (int db = 0; db < 4; ++db) {
        const int scf = ((ks * 4 + quad) ^ (l15 & 7)) * 8;
        const bf16x8_t vf = *(const bf16x8_t*)&Vl[(db * 16 + l15) * 64 + scf];
#pragma unroll
        for (int qh = 0; qh < 2; ++qh)
          o[qh][db] = __builtin_amdgcn_mfma_f32_16x16x32_bf16(vf, pf[qh][ks], o[qh][db], 0, 0, 0);
      }
    }
    bc = (bc + 1 == 3) ? 0 : bc + 1;
  }

#pragma unroll
  for (int qh = 0; qh < 2; ++qh) {
    li[qh] += __shfl_xor(li[qh], 16);
    li[qh] += __shfl_xor(li[qh], 32);
    const long pr = prow0 + qw + qh * 16 + l15;
#pragma unroll
    for (int db = 0; db < 4; ++db)
      *(f32x4_t*)&po[pr * 64 + db * 16 + quad * 4] = o[qh][db];
    if (quad == 0) pl[pr] = li[qh];
  }
}

// ---------------------------------------------------------------------------
// Merge the 2 split-K partials: out = (o0+o1)/(l0+l1) -> bf16 [token][512].
// ---------------------------------------------------------------------------
__global__ __launch_bounds__(256) void merge_attn(const float* __restrict__ po,
                                                  const float* __restrict__ pl,
                                                  bf16_t* __restrict__ O) {
  const int qt = blockIdx.x, bh = blockIdx.y, b = bh >> 3, h = bh & 7;
  const int t = threadIdx.x;
  const int q = qt * 64 + (t >> 2), d0 = (t & 3) * 16;
  const long r0 = (long)bh * 2048 + q;
  const long r1 = (long)(16 + bh) * 2048 + q;
  const float inv = 1.0f / (pl[r0] + pl[r1]);
  const long i0 = r0 * 64 + d0;
  const long i1 = r1 * 64 + d0;
  alignas(16) bf16_t out[16];
#pragma unroll
  for (int j = 0; j < 4; ++j) {
    f32x4_t a = *(const f32x4_t*)&po[i0 + j * 4];
    f32x4_t c = *(const f32x4_t*)&po[i1 + j * 4];
#pragma unroll
    for (int r = 0; r < 4; ++r) out[j * 4 + r] = (bf16_t)((a[r] + c[r]) * inv);
  }
  const long row = (long)b * S_ + q;
  *(uint4*)(O + row * D_ + h * DK_ + d0) = *(uint4*)&out[0];
  *(uint4*)(O + row * D_ + h * DK_ + d0 + 8) = *(uint4*)&out[8];
}

// ---------------------------------------------------------------------------
extern "C" void kernel_launch(void* const* d_in, const int* in_sizes, int n_in,
                              void* d_out, int out_size, void* d_ws, size_t ws_size,
                              hipStream_t stream) {
  const float* x    = (const float*)d_in[0];
  const float* enc  = (const float*)d_in[1];
  const float* saWq = (const float*)d_in[4];  const float* sabq = (const float*)d_in[5];
  const float* saWk = (const float*)d_in[6];  const float* sabk = (const float*)d_in[7];
  const float* saWv = (const float*)d_in[8];  const float* sabv = (const float*)d_in[9];
  const float* saWo = (const float*)d_in[10]; const float* sabo = (const float*)d_in[11];
  const float* caWq = (const float*)d_in[12]; const float* cabq = (const float*)d_in[13];
  const float* caWk = (const float*)d_in[14]; const float* cabk = (const float*)d_in[15];
  const float* caWv = (const float*)d_in[16]; const float* cabv = (const float*)d_in[17];
  const float* caWo = (const float*)d_in[18]; const float* cabo = (const float*)d_in[19];
  const float* ffW1 = (const float*)d_in[20]; const float* ffb1 = (const float*)d_in[21];
  const float* ffW2 = (const float*)d_in[22]; const float* ffb2 = (const float*)d_in[23];
  const float* ln0a = (const float*)d_in[24]; const float* ln0b = (const float*)d_in[25];
  const float* ln1a = (const float*)d_in[26]; const float* ln1b = (const float*)d_in[27];
  const float* ln2a = (const float*)d_in[28]; const float* ln2b = (const float*)d_in[29];

  char* ws = (char*)d_ws;
  size_t off = 0;
  auto alloc = [&](size_t bytes) -> void* {
    void* p = ws + off;
    off += (bytes + 255) & ~(size_t)255;
    return p;
  };
  bf16_t* wt_saq = (bf16_t*)alloc(512 * 512 * 2);
  bf16_t* wt_sak = (bf16_t*)alloc(512 * 512 * 2);
  bf16_t* wt_sav = (bf16_t*)alloc(512 * 512 * 2);
  bf16_t* wt_sao = (bf16_t*)alloc(512 * 512 * 2);
  bf16_t* wt_caq = (bf16_t*)alloc(512 * 512 * 2);
  bf16_t* wt_cak = (bf16_t*)alloc(512 * 512 * 2);
  bf16_t* wt_cav = (bf16_t*)alloc(512 * 512 * 2);
  bf16_t* wt_cao = (bf16_t*)alloc(512 * 512 * 2);
  bf16_t* wt_f1  = (bf16_t*)alloc((size_t)512 * 2048 * 2);
  bf16_t* wt_f2  = (bf16_t*)alloc((size_t)2048 * 512 * 2);
  bf16_t* enc_b  = (bf16_t*)alloc((size_t)M_ * D_ * 2);
  bf16_t* nbuf   = (bf16_t*)alloc((size_t)M_ * D_ * 2);
  bf16_t* qb     = (bf16_t*)alloc((size_t)M_ * D_ * 2);
  bf16_t* kb     = (bf16_t*)alloc((size_t)M_ * D_ * 2);
  bf16_t* vb     = (bf16_t*)alloc((size_t)M_ * D_ * 2);
  bf16_t* vtb    = (bf16_t*)alloc((size_t)M_ * D_ * 2);
  bf16_t* attnb  = (bf16_t*)alloc((size_t)M_ * D_ * 2);
  bf16_t* hid    = (bf16_t*)alloc((size_t)M_ * DFF_ * 2);  // aliases po
  float*  x1     = (float*)alloc((size_t)M_ * D_ * 4);
  float*  x2     = (float*)alloc((size_t)M_ * D_ * 4);
  float*  pl     = (float*)alloc(2 * 16 * 2048 * 4);
  float*  po     = (float*)hid;  // 16.78 MB, free until FFN phase

  // Weight prep + encoder convert (same every call; graph-safe).
  {
    WPA a;
    a.W[0] = saWq; a.T[0] = wt_saq;
    a.W[1] = saWk; a.T[1] = wt_sak;
    a.W[2] = saWv; a.T[2] = wt_sav;
    a.W[3] = saWo; a.T[3] = wt_sao;
    a.W[4] = caWq; a.T[4] = wt_caq;
    a.W[5] = caWk; a.T[5] = wt_cak;
    a.W[6] = caWv; a.T[6] = wt_cav;
    a.W[7] = caWo; a.T[7] = wt_cao;
    a.W[8] = ffW1; a.T[8] = wt_f1;
    a.W[9] = ffW2; a.T[9] = wt_f2;
    wprep<<<1024, 256, 0, stream>>>(a);
  }
  cvt_bf16<<<1024, 256, 0, stream>>>(enc, enc_b);

  // Residual 0: self-attention
  ln_kernel<<<1024, 256, 0, stream>>>(x, ln0a, ln0b, nbuf);
  {
    GArg z0{nbuf, wt_saq, sabq, nullptr, qb, QSCALE};
    GArg z1{nbuf, wt_sak, sabk, nullptr, kb, 1.0f};
    GArg z2{nbuf, wt_sav, sabv, nullptr, vb, 1.0f};
    gemm_bt<0><<<dim3(64, 4, 3), 256, 0, stream>>>(z0, z1, z2, M_, 512, 512);
  }
  vtrans<<<dim3(32, 16), 256, 0, stream>>>(vb, vtb);
  flash_attn<true><<<dim3(16, 16, 2), 256, 0, stream>>>(qb, kb, vtb, po, pl);
  merge_attn<<<dim3(32, 16), 256, 0, stream>>>(po, pl, attnb);
  {
    GArg o1{attnb, wt_sao, sabo, x, x1, 1.0f};
    gemm_bt<2><<<dim3(64, 4, 1), 256, 0, stream>>>(o1, o1, o1, M_, 512, 512);
  }

  // Residual 1: cross-attention (K,V from raw encoder_output)
  ln_kernel<<<1024, 256, 0, stream>>>(x1, ln1a, ln1b, nbuf);
  {
    GArg c0{nbuf,  wt_caq, cabq, nullptr, qb, QSCALE};
    GArg c1{enc_b, wt_cak, cabk, nullptr, kb, 1.0f};
    GArg c2{enc_b, wt_cav, cabv, nullptr, vb, 1.0f};
    gemm_bt<0><<<dim3(64, 4, 3), 256, 0, stream>>>(c0, c1, c2, M_, 512, 512);
  }
  vtrans<<<dim3(32, 16), 256, 0, stream>>>(vb, vtb);
  flash_attn<false><<<dim3(16, 16, 2), 256, 0, stream>>>(qb, kb, vtb, po, pl);
  merge_attn<<<dim3(32, 16), 256, 0, stream>>>(po, pl, attnb);
  {
    GArg o2{attnb, wt_cao, cabo, x1, x2, 1.0f};
    gemm_bt<2><<<dim3(64, 4, 1), 256, 0, stream>>>(o2, o2, o2, M_, 512, 512);
  }

  // Residual 2: FFN (hid aliases po — po is dead after the cross merge)
  ln_kernel<<<1024, 256, 0, stream>>>(x2, ln2a, ln2b, nbuf);
  {
    GArg f1{nbuf, wt_f1, ffb1, nullptr, hid, 1.0f};
    gemm_bt<1><<<dim3(64, 16, 1), 256, 0, stream>>>(f1, f1, f1, M_, DFF_, 512);
  }
  {
    GArg f2{hid, wt_f2, ffb2, x2, d_out, 1.0f};
    gemm_bt<2><<<dim3(64, 4, 1), 256, 0, stream>>>(f2, f2, f2, M_, 512, DFF_);
  }
}